// Round 8
// baseline (254.895 us; speedup 1.0000x reference)
//
#include <hip/hip_runtime.h>

// Problem dims (fixed by reference setup_inputs)
#define B_  4
#define C_  3
#define S_  5
#define M_  18
#define HW  45056            // 256*176
#define HW4 (HW/4)           // 11264 float4s per plane/channel
#define SPLIT 4              // blocks per (b,s,m) plane (divides HW4/TPB = 44)
#define TPB 256
#define CHUNK4 (HW4/SPLIT)   // 2816 float4s per block
#define ITERS (CHUNK4/TPB)   // 11 iterations per thread
#define NPLANE (B_*S_*M_)    // 360
#define NBLK (NPLANE*SPLIT)  // 1440 blocks (1440 % 8 == 0 -> bijective XCD swizzle)

// clang ext-vector so __builtin_nontemporal_load works (HIP float4 is a struct)
typedef float f4 __attribute__((ext_vector_type(4)));

// Design ledger (measured on MI355X):
//  - Two kernels, not flag-fused: fusion costs a buffer_wbl2 fence storm
//    (R4: 45us idle) or sc1 scalar-load serialization (R5: 70us).
//  - Interleaved 7-stream loop, ITERS=11: best measured base (R6).
//    Register-staging the mask regressed ~8us (R7: VGPR 88 -> 5 waves/SIMD).
//  - R7 counters: latency-bound, all pipes <25%. Fixes here:
//    (a) __launch_bounds__(256,8): VGPR<=64 -> 8 waves/SIMD -> all 5760
//        waves co-resident (TLP is the latency lever, not per-wave ILP);
//    (b) nt on MASK loads only: zero-reuse 8MB/XCD stream marked evict-first
//        so it stops flushing the 1.08MB X/Y set out of each XCD's L2.
__global__ __launch_bounds__(TPB, 8) void moments_kernel(
    const float4* __restrict__ X, const float4* __restrict__ Y,
    const f4* __restrict__ Mk, float* __restrict__ part) {
  // XCD-aware bijective swizzle: each XCD's L2 holds ~1 batch of X/Y.
  int wg    = (blockIdx.x & 7) * (NBLK / 8) + (blockIdx.x >> 3);
  int plane = wg / SPLIT;           // (b,s,m)
  int chunk = wg - plane * SPLIT;
  int b     = plane / (S_ * M_);

  const f4*     mp = Mk + (size_t)plane * HW4;
  const float4* xp = X  + (size_t)b * (C_ * HW4);
  const float4* yp = Y  + (size_t)b * (C_ * HW4);

  int base = chunk * CHUNK4 + (int)threadIdx.x;

  float aW = 0.f;
  float a1[C_], a2[C_], a11[C_], a22[C_], a12[C_];
#pragma unroll
  for (int c = 0; c < C_; ++c) { a1[c]=a2[c]=a11[c]=a22[c]=a12[c]=0.f; }

#pragma unroll
  for (int it = 0; it < ITERS; ++it) {
    int i = base + it * TPB;
    // nt: evict-first in L2 — the mask has zero reuse; protect X/Y residency.
    f4 w = __builtin_nontemporal_load(mp + i);
    aW += (w.x + w.y) + (w.z + w.w);
    float wf[4] = {w.x, w.y, w.z, w.w};
#pragma unroll
    for (int c = 0; c < C_; ++c) {
      float4 xv = xp[c * HW4 + i];
      float4 yv = yp[c * HW4 + i];
      float xf[4] = {xv.x, xv.y, xv.z, xv.w};
      float yf[4] = {yv.x, yv.y, yv.z, yv.w};
#pragma unroll
      for (int j = 0; j < 4; ++j) {
        float xc = xf[j], yc = yf[j], wc = wf[j];
        float wx = wc * xc;
        float wy = wc * yc;
        a1 [c] += wx;
        a2 [c] += wy;
        a11[c]  = fmaf(wx, xc, a11[c]);
        a22[c]  = fmaf(wy, yc, a22[c]);
        a12[c]  = fmaf(wx, yc, a12[c]);
      }
    }
  }

  // Pack 16 values: [0]=msum, then per channel {wx, wy, wxx, wyy, wxy} (raw)
  float v[16];
  v[0] = aW;
#pragma unroll
  for (int c = 0; c < C_; ++c) {
    v[1 + c*5 + 0] = a1[c];
    v[1 + c*5 + 1] = a2[c];
    v[1 + c*5 + 2] = a11[c];
    v[1 + c*5 + 3] = a22[c];
    v[1 + c*5 + 4] = a12[c];
  }

  // wave-64 butterfly reduce (amortized over the 11-iter main loop)
#pragma unroll
  for (int off = 32; off > 0; off >>= 1) {
#pragma unroll
    for (int j = 0; j < 16; ++j) v[j] += __shfl_xor(v[j], off);
  }

  __shared__ float red[TPB/64][16];
  int lane = threadIdx.x & 63;
  int wv   = threadIdx.x >> 6;
  if (lane == 0) {
#pragma unroll
    for (int j = 0; j < 16; ++j) red[wv][j] = v[j];
  }
  __syncthreads();
  if (threadIdx.x < 16) {
    float s = (red[0][threadIdx.x] + red[1][threadIdx.x]) +
              (red[2][threadIdx.x] + red[3][threadIdx.x]);
    part[(size_t)wg * 16 + threadIdx.x] = s;
  }
}

// Kernel B: tiny epilogue, one block. Plain loads (kernel-boundary coherence).
// Exact affine rescale of raw moments in double:
//   xs = 0.5x + 0.5  =>  E[w*xs]    = 0.5*S1 + 0.5*W
//                        E[w*xs^2]  = 0.25*S11 + 0.5*S1 + 0.25*W
//                        E[w*xs*ys] = 0.25*(S12 + S1 + S2 + W)
__global__ __launch_bounds__(384) void finalize_kernel(
    const float* __restrict__ part, float* __restrict__ out) {
  __shared__ float csS[NPLANE], ssS[NPLANE];
  __shared__ double csb[B_*S_], ssb[B_*S_];
  int t = threadIdx.x;

  if (t < NPLANE) {
    double s[16];
#pragma unroll
    for (int j = 0; j < 16; ++j) s[j] = 0.0;
    for (int ch = 0; ch < SPLIT; ++ch) {
      const float* p = part + (size_t)(t * SPLIT + ch) * 16;
#pragma unroll
      for (int j = 0; j < 16; ++j) s[j] += (double)p[j];
    }
    const double C1d = 1e-4, C2d = 9e-4;
    double W = s[0];
    double inv = 1.0 / (W + 1e-6);
    double csAcc = 0.0, ssAcc = 0.0;
#pragma unroll
    for (int c = 0; c < C_; ++c) {
      double S1  = s[1 + c*5 + 0];
      double S2  = s[1 + c*5 + 1];
      double S11 = s[1 + c*5 + 2];
      double S22 = s[1 + c*5 + 3];
      double S12 = s[1 + c*5 + 4];
      double mu1  = (0.5*S1 + 0.5*W) * inv;
      double mu2  = (0.5*S2 + 0.5*W) * inv;
      double mu11 = (0.25*S11 + 0.5*S1 + 0.25*W) * inv;
      double mu22 = (0.25*S22 + 0.5*S2 + 0.25*W) * inv;
      double mu12 = (0.25*(S12 + S1 + S2 + W)) * inv;
      double m1s = mu1*mu1, m2s = mu2*mu2, m12 = mu1*mu2;
      double sig1  = mu11 - m1s;
      double sig2  = mu22 - m2s;
      double sig12 = mu12 - m12;
      double cs   = (2.0*sig12 + C2d) / (sig1 + sig2 + C2d);
      double ssim = (2.0*m12 + C1d) / (m1s + m2s + C1d) * cs;
      if (cs   < 0.0) cs   = 0.0;
      if (ssim < 0.0) ssim = 0.0;
      csAcc += cs; ssAcc += ssim;
    }
    csS[t] = (float)csAcc;
    ssS[t] = (float)ssAcc;
  }
  __syncthreads();

  if (t < B_*S_) {  // t = b*S_ + s
    double cb = 0.0, sb = 0.0;
    for (int m = 0; m < M_; ++m) { cb += (double)csS[t*M_ + m]; sb += (double)ssS[t*M_ + m]; }
    csb[t] = cb / (double)(M_*C_);
    ssb[t] = sb / (double)(M_*C_);
  }
  __syncthreads();

  if (t == 0) {
    double acc = 0.0;
    for (int b = 0; b < B_; ++b) {
      double p = ssb[b*S_ + (S_-1)];
      for (int s = 0; s < S_-1; ++s) p *= csb[b*S_ + s];
      acc += p;
    }
    out[0] = (float)(acc / (double)B_);
  }
}

extern "C" void kernel_launch(void* const* d_in, const int* in_sizes, int n_in,
                              void* d_out, int out_size, void* d_ws, size_t ws_size,
                              hipStream_t stream) {
  (void)in_sizes; (void)n_in; (void)out_size; (void)ws_size;
  const float4* X  = (const float4*)d_in[0];
  const float4* Y  = (const float4*)d_in[1];
  const f4*     Mk = (const f4*)d_in[2];
  float* part = (float*)d_ws;        // 1440*16*4 = 92160 B
  float* out  = (float*)d_out;

  hipLaunchKernelGGL(moments_kernel, dim3(NBLK), dim3(TPB), 0, stream,
                     X, Y, Mk, part);
  hipLaunchKernelGGL(finalize_kernel, dim3(1), dim3(384), 0, stream, part, out);
}

// Round 9
// 124.886 us; speedup vs baseline: 2.0410x; 2.0410x over previous
//
#include <hip/hip_runtime.h>

// Problem dims (fixed by reference setup_inputs)
#define B_  4
#define C_  3
#define S_  5
#define M_  18
#define HW  45056            // 256*176
#define HW4 (HW/4)           // 11264 float4s per plane/channel
#define SPLIT 4              // blocks per (b,s,m) plane (divides HW4/TPB = 44)
#define TPB 256
#define CHUNK4 (HW4/SPLIT)   // 2816 float4s per block
#define ITERS (CHUNK4/TPB)   // 11 iterations per thread
#define NPLANE (B_*S_*M_)    // 360
#define NBLK (NPLANE*SPLIT)  // 1440 blocks (1440 % 8 == 0 -> bijective XCD swizzle)

// clang ext-vector so __builtin_nontemporal_load works (HIP float4 is a struct)
typedef float f4 __attribute__((ext_vector_type(4)));

// Design ledger (measured on MI355X):
//  - Two kernels, not flag-fused: fusion costs a buffer_wbl2 fence storm
//    (R4: 45us idle) or sc1 scalar-load serialization (R5: 70us).
//  - Interleaved 7-stream loop, ITERS=11, 1440 blocks: best base (R6, 116.4).
//  - Mask reg-staging: -8us (R7, VGPR 88). NEVER force VGPR below ~64 here:
//    __launch_bounds__(256,8) -> VGPR 32 -> accumulator spill, 305MB scratch
//    writes, 166us (R8). Occupancy rose (54%) but spills swamped it.
//  - This round: R6 + nt on the MASK stream ONLY (single-variable A/B).
//    R7's FETCH=36MB >> 4MB ideal implies X/Y refetched ~4x/XCD — the 8MB/XCD
//    zero-reuse mask stream evicts the 1.08MB X/Y set from each 4MiB L2.
//    nt = evict-first/no-allocate: mask still hits L3 (restore-copy resident),
//    X/Y stay genuine L2 hits.
__global__ __launch_bounds__(TPB) void moments_kernel(
    const float4* __restrict__ X, const float4* __restrict__ Y,
    const f4* __restrict__ Mk, float* __restrict__ part) {
  // XCD-aware bijective swizzle: each XCD's L2 holds ~1 batch of X/Y.
  int wg    = (blockIdx.x & 7) * (NBLK / 8) + (blockIdx.x >> 3);
  int plane = wg / SPLIT;           // (b,s,m)
  int chunk = wg - plane * SPLIT;
  int b     = plane / (S_ * M_);

  const f4*     mp = Mk + (size_t)plane * HW4;
  const float4* xp = X  + (size_t)b * (C_ * HW4);
  const float4* yp = Y  + (size_t)b * (C_ * HW4);

  int base = chunk * CHUNK4 + (int)threadIdx.x;

  float aW = 0.f;
  float a1[C_], a2[C_], a11[C_], a22[C_], a12[C_];
#pragma unroll
  for (int c = 0; c < C_; ++c) { a1[c]=a2[c]=a11[c]=a22[c]=a12[c]=0.f; }

#pragma unroll
  for (int it = 0; it < ITERS; ++it) {
    int i = base + it * TPB;
    // nt: zero-reuse mask marked evict-first; protects X/Y L2 residency.
    f4 w = __builtin_nontemporal_load(mp + i);
    aW += (w.x + w.y) + (w.z + w.w);
    float wf[4] = {w.x, w.y, w.z, w.w};
#pragma unroll
    for (int c = 0; c < C_; ++c) {
      float4 xv = xp[c * HW4 + i];
      float4 yv = yp[c * HW4 + i];
      float xf[4] = {xv.x, xv.y, xv.z, xv.w};
      float yf[4] = {yv.x, yv.y, yv.z, yv.w};
#pragma unroll
      for (int j = 0; j < 4; ++j) {
        float xc = xf[j], yc = yf[j], wc = wf[j];
        float wx = wc * xc;
        float wy = wc * yc;
        a1 [c] += wx;
        a2 [c] += wy;
        a11[c]  = fmaf(wx, xc, a11[c]);
        a22[c]  = fmaf(wy, yc, a22[c]);
        a12[c]  = fmaf(wx, yc, a12[c]);
      }
    }
  }

  // Pack 16 values: [0]=msum, then per channel {wx, wy, wxx, wyy, wxy} (raw)
  float v[16];
  v[0] = aW;
#pragma unroll
  for (int c = 0; c < C_; ++c) {
    v[1 + c*5 + 0] = a1[c];
    v[1 + c*5 + 1] = a2[c];
    v[1 + c*5 + 2] = a11[c];
    v[1 + c*5 + 3] = a22[c];
    v[1 + c*5 + 4] = a12[c];
  }

  // wave-64 butterfly reduce (amortized over the 11-iter main loop)
#pragma unroll
  for (int off = 32; off > 0; off >>= 1) {
#pragma unroll
    for (int j = 0; j < 16; ++j) v[j] += __shfl_xor(v[j], off);
  }

  __shared__ float red[TPB/64][16];
  int lane = threadIdx.x & 63;
  int wv   = threadIdx.x >> 6;
  if (lane == 0) {
#pragma unroll
    for (int j = 0; j < 16; ++j) red[wv][j] = v[j];
  }
  __syncthreads();
  if (threadIdx.x < 16) {
    float s = (red[0][threadIdx.x] + red[1][threadIdx.x]) +
              (red[2][threadIdx.x] + red[3][threadIdx.x]);
    part[(size_t)wg * 16 + threadIdx.x] = s;
  }
}

// Kernel B: tiny epilogue, one block. Plain loads (kernel-boundary coherence).
// Exact affine rescale of raw moments in double:
//   xs = 0.5x + 0.5  =>  E[w*xs]    = 0.5*S1 + 0.5*W
//                        E[w*xs^2]  = 0.25*S11 + 0.5*S1 + 0.25*W
//                        E[w*xs*ys] = 0.25*(S12 + S1 + S2 + W)
__global__ __launch_bounds__(384) void finalize_kernel(
    const float* __restrict__ part, float* __restrict__ out) {
  __shared__ float csS[NPLANE], ssS[NPLANE];
  __shared__ double csb[B_*S_], ssb[B_*S_];
  int t = threadIdx.x;

  if (t < NPLANE) {
    double s[16];
#pragma unroll
    for (int j = 0; j < 16; ++j) s[j] = 0.0;
    for (int ch = 0; ch < SPLIT; ++ch) {
      const float* p = part + (size_t)(t * SPLIT + ch) * 16;
#pragma unroll
      for (int j = 0; j < 16; ++j) s[j] += (double)p[j];
    }
    const double C1d = 1e-4, C2d = 9e-4;
    double W = s[0];
    double inv = 1.0 / (W + 1e-6);
    double csAcc = 0.0, ssAcc = 0.0;
#pragma unroll
    for (int c = 0; c < C_; ++c) {
      double S1  = s[1 + c*5 + 0];
      double S2  = s[1 + c*5 + 1];
      double S11 = s[1 + c*5 + 2];
      double S22 = s[1 + c*5 + 3];
      double S12 = s[1 + c*5 + 4];
      double mu1  = (0.5*S1 + 0.5*W) * inv;
      double mu2  = (0.5*S2 + 0.5*W) * inv;
      double mu11 = (0.25*S11 + 0.5*S1 + 0.25*W) * inv;
      double mu22 = (0.25*S22 + 0.5*S2 + 0.25*W) * inv;
      double mu12 = (0.25*(S12 + S1 + S2 + W)) * inv;
      double m1s = mu1*mu1, m2s = mu2*mu2, m12 = mu1*mu2;
      double sig1  = mu11 - m1s;
      double sig2  = mu22 - m2s;
      double sig12 = mu12 - m12;
      double cs   = (2.0*sig12 + C2d) / (sig1 + sig2 + C2d);
      double ssim = (2.0*m12 + C1d) / (m1s + m2s + C1d) * cs;
      if (cs   < 0.0) cs   = 0.0;
      if (ssim < 0.0) ssim = 0.0;
      csAcc += cs; ssAcc += ssim;
    }
    csS[t] = (float)csAcc;
    ssS[t] = (float)ssAcc;
  }
  __syncthreads();

  if (t < B_*S_) {  // t = b*S_ + s
    double cb = 0.0, sb = 0.0;
    for (int m = 0; m < M_; ++m) { cb += (double)csS[t*M_ + m]; sb += (double)ssS[t*M_ + m]; }
    csb[t] = cb / (double)(M_*C_);
    ssb[t] = sb / (double)(M_*C_);
  }
  __syncthreads();

  if (t == 0) {
    double acc = 0.0;
    for (int b = 0; b < B_; ++b) {
      double p = ssb[b*S_ + (S_-1)];
      for (int s = 0; s < S_-1; ++s) p *= csb[b*S_ + s];
      acc += p;
    }
    out[0] = (float)(acc / (double)B_);
  }
}

extern "C" void kernel_launch(void* const* d_in, const int* in_sizes, int n_in,
                              void* d_out, int out_size, void* d_ws, size_t ws_size,
                              hipStream_t stream) {
  (void)in_sizes; (void)n_in; (void)out_size; (void)ws_size;
  const float4* X  = (const float4*)d_in[0];
  const float4* Y  = (const float4*)d_in[1];
  const f4*     Mk = (const f4*)d_in[2];
  float* part = (float*)d_ws;        // 1440*16*4 = 92160 B
  float* out  = (float*)d_out;

  hipLaunchKernelGGL(moments_kernel, dim3(NBLK), dim3(TPB), 0, stream,
                     X, Y, Mk, part);
  hipLaunchKernelGGL(finalize_kernel, dim3(1), dim3(384), 0, stream, part, out);
}

// Round 10
// 124.089 us; speedup vs baseline: 2.0541x; 1.0064x over previous
//
#include <hip/hip_runtime.h>

// Problem dims (fixed by reference setup_inputs)
#define B_  4
#define C_  3
#define S_  5
#define M_  18
#define HW  45056            // 256*176
#define HW4 (HW/4)           // 11264 float4s per plane/channel
#define SPLIT 4              // chunks per plane-group (ITERS=11 proven best)
#define TPB 768              // 3 groups x 256 threads (12 waves/block)
#define GTPB 256             // threads per plane-group
#define G   3                // m-planes per block, one per thread-group
#define MG  (M_/G)           // 6 m-groups per (b,s)
#define CHUNK4 (HW4/SPLIT)   // 2816 float4s per chunk
#define ITERS (CHUNK4/GTPB)  // 11 iterations per thread
#define NGROUP (B_*S_*MG)    // 120 plane-groups
#define NBLK (NGROUP*SPLIT)  // 480 blocks (480 % 8 == 0 -> bijective XCD swizzle)
#define NPLANE (B_*S_*M_)    // 360

// Design ledger (measured on MI355X):
//  - Two kernels, not flag-fused: fusion costs a buffer_wbl2 fence storm
//    (R4: 45us idle) or sc1 scalar-load serialization (R5: 70us).
//  - ITERS=11, plain cached loads, 16-val butterfly: champion base (R6, 116.4).
//  - nt on mask: +8.5us (R9 clean A/B) — forfeits L3 residency. DEAD.
//  - Mask reg-staging: +8us (R7). Forcing VGPR<=32: spills, +130us (R8).
//  - Register-G-sharing (R1/R2): cut waves 3x -> latency-bound. DEAD.
//  - THIS round: L1-level G-sharing. 3 thread-groups per block process 3
//    planes of the same (b,s,chunk); groups read IDENTICAL X/Y addresses in
//    lockstep (__syncthreads per iter) -> X/Y fetched once into L1/L2, hit
//    3x. Wave count stays 5760 (=R6); per-thread work unchanged; only the
//    cross-block X/Y re-read traffic (389MB -> ~130MB) changes.
__global__ __launch_bounds__(TPB) void moments_kernel(
    const float4* __restrict__ X, const float4* __restrict__ Y,
    const float4* __restrict__ Mk, float* __restrict__ part) {
  // XCD-aware bijective swizzle: each XCD's L2 holds ~1 batch of X/Y.
  int wg    = (blockIdx.x & 7) * (NBLK / 8) + (blockIdx.x >> 3);
  int pg    = wg / SPLIT;            // (b, s, mg)
  int chunk = wg - pg * SPLIT;
  int bs    = pg / MG;               // b*S_ + s
  int mg    = pg - bs * MG;
  int b     = bs / S_;

  int grp  = threadIdx.x >> 8;       // 0..2 : which m-plane
  int gtid = threadIdx.x & 255;      // 0..255 within group

  int plane = bs * M_ + mg * G + grp;            // global plane id
  const float4* mp = Mk + (size_t)plane * HW4;
  const float4* xp = X  + (size_t)b * (C_ * HW4);
  const float4* yp = Y  + (size_t)b * (C_ * HW4);

  int base = chunk * CHUNK4 + gtid;

  float aW = 0.f;
  float a1[C_], a2[C_], a11[C_], a22[C_], a12[C_];
#pragma unroll
  for (int c = 0; c < C_; ++c) { a1[c]=a2[c]=a11[c]=a22[c]=a12[c]=0.f; }

#pragma unroll
  for (int it = 0; it < ITERS; ++it) {
    // Keep the 3 groups in lockstep so their identical X/Y reads coalesce
    // in L1 (32KB/CU; per-iter X/Y working set = 24KB).
    __syncthreads();
    int i = base + it * GTPB;
    float4 w = mp[i];                // per-group mask plane (L3-resident)
    aW += (w.x + w.y) + (w.z + w.w);
    float wf[4] = {w.x, w.y, w.z, w.w};
#pragma unroll
    for (int c = 0; c < C_; ++c) {
      float4 xv = xp[c * HW4 + i];   // same address in all 3 groups -> L1 hit
      float4 yv = yp[c * HW4 + i];
      float xf[4] = {xv.x, xv.y, xv.z, xv.w};
      float yf[4] = {yv.x, yv.y, yv.z, yv.w};
#pragma unroll
      for (int j = 0; j < 4; ++j) {
        float xc = xf[j], yc = yf[j], wc = wf[j];
        float wx = wc * xc;
        float wy = wc * yc;
        a1 [c] += wx;
        a2 [c] += wy;
        a11[c]  = fmaf(wx, xc, a11[c]);
        a22[c]  = fmaf(wy, yc, a22[c]);
        a12[c]  = fmaf(wx, yc, a12[c]);
      }
    }
  }

  // Pack 16 values: [0]=msum, then per channel {wx, wy, wxx, wyy, wxy} (raw)
  float v[16];
  v[0] = aW;
#pragma unroll
  for (int c = 0; c < C_; ++c) {
    v[1 + c*5 + 0] = a1[c];
    v[1 + c*5 + 1] = a2[c];
    v[1 + c*5 + 2] = a11[c];
    v[1 + c*5 + 3] = a22[c];
    v[1 + c*5 + 4] = a12[c];
  }

  // wave-64 butterfly reduce (16 values, amortized over 11 iters)
#pragma unroll
  for (int off = 32; off > 0; off >>= 1) {
#pragma unroll
    for (int j = 0; j < 16; ++j) v[j] += __shfl_xor(v[j], off);
  }

  __shared__ float red[TPB/64][16];            // 12 waves x 16
  int lane = threadIdx.x & 63;
  int wv   = threadIdx.x >> 6;                 // global wave id 0..11
  if (lane == 0) {
#pragma unroll
    for (int j = 0; j < 16; ++j) red[wv][j] = v[j];
  }
  __syncthreads();
  if (gtid < 16) {
    int w0 = grp * 4;                          // this group's 4 waves
    float s = (red[w0+0][gtid] + red[w0+1][gtid]) +
              (red[w0+2][gtid] + red[w0+3][gtid]);
    // plane-major layout, same as champion: part[(plane*SPLIT+chunk)*16 + j]
    part[(size_t)(plane * SPLIT + chunk) * 16 + gtid] = s;
  }
}

// Kernel B: tiny epilogue, one block. Plain loads (kernel-boundary coherence).
// Exact affine rescale of raw moments in double:
//   xs = 0.5x + 0.5  =>  E[w*xs]    = 0.5*S1 + 0.5*W
//                        E[w*xs^2]  = 0.25*S11 + 0.5*S1 + 0.25*W
//                        E[w*xs*ys] = 0.25*(S12 + S1 + S2 + W)
__global__ __launch_bounds__(384) void finalize_kernel(
    const float* __restrict__ part, float* __restrict__ out) {
  __shared__ float csS[NPLANE], ssS[NPLANE];
  __shared__ double csb[B_*S_], ssb[B_*S_];
  int t = threadIdx.x;

  if (t < NPLANE) {
    double s[16];
#pragma unroll
    for (int j = 0; j < 16; ++j) s[j] = 0.0;
    for (int ch = 0; ch < SPLIT; ++ch) {
      const float* p = part + (size_t)(t * SPLIT + ch) * 16;
#pragma unroll
      for (int j = 0; j < 16; ++j) s[j] += (double)p[j];
    }
    const double C1d = 1e-4, C2d = 9e-4;
    double W = s[0];
    double inv = 1.0 / (W + 1e-6);
    double csAcc = 0.0, ssAcc = 0.0;
#pragma unroll
    for (int c = 0; c < C_; ++c) {
      double S1  = s[1 + c*5 + 0];
      double S2  = s[1 + c*5 + 1];
      double S11 = s[1 + c*5 + 2];
      double S22 = s[1 + c*5 + 3];
      double S12 = s[1 + c*5 + 4];
      double mu1  = (0.5*S1 + 0.5*W) * inv;
      double mu2  = (0.5*S2 + 0.5*W) * inv;
      double mu11 = (0.25*S11 + 0.5*S1 + 0.25*W) * inv;
      double mu22 = (0.25*S22 + 0.5*S2 + 0.25*W) * inv;
      double mu12 = (0.25*(S12 + S1 + S2 + W)) * inv;
      double m1s = mu1*mu1, m2s = mu2*mu2, m12 = mu1*mu2;
      double sig1  = mu11 - m1s;
      double sig2  = mu22 - m2s;
      double sig12 = mu12 - m12;
      double cs   = (2.0*sig12 + C2d) / (sig1 + sig2 + C2d);
      double ssim = (2.0*m12 + C1d) / (m1s + m2s + C1d) * cs;
      if (cs   < 0.0) cs   = 0.0;
      if (ssim < 0.0) ssim = 0.0;
      csAcc += cs; ssAcc += ssim;
    }
    csS[t] = (float)csAcc;
    ssS[t] = (float)ssAcc;
  }
  __syncthreads();

  if (t < B_*S_) {  // t = b*S_ + s
    double cb = 0.0, sb = 0.0;
    for (int m = 0; m < M_; ++m) { cb += (double)csS[t*M_ + m]; sb += (double)ssS[t*M_ + m]; }
    csb[t] = cb / (double)(M_*C_);
    ssb[t] = sb / (double)(M_*C_);
  }
  __syncthreads();

  if (t == 0) {
    double acc = 0.0;
    for (int b = 0; b < B_; ++b) {
      double p = ssb[b*S_ + (S_-1)];
      for (int s = 0; s < S_-1; ++s) p *= csb[b*S_ + s];
      acc += p;
    }
    out[0] = (float)(acc / (double)B_);
  }
}

extern "C" void kernel_launch(void* const* d_in, const int* in_sizes, int n_in,
                              void* d_out, int out_size, void* d_ws, size_t ws_size,
                              hipStream_t stream) {
  (void)in_sizes; (void)n_in; (void)out_size; (void)ws_size;
  const float4* X  = (const float4*)d_in[0];
  const float4* Y  = (const float4*)d_in[1];
  const float4* Mk = (const float4*)d_in[2];
  float* part = (float*)d_ws;        // 1440*16*4 = 92160 B
  float* out  = (float*)d_out;

  hipLaunchKernelGGL(moments_kernel, dim3(NBLK), dim3(TPB), 0, stream,
                     X, Y, Mk, part);
  hipLaunchKernelGGL(finalize_kernel, dim3(1), dim3(384), 0, stream, part, out);
}

// Round 11
// 121.297 us; speedup vs baseline: 2.1014x; 1.0230x over previous
//
#include <hip/hip_runtime.h>

// Problem dims (fixed by reference setup_inputs)
#define B_  4
#define C_  3
#define S_  5
#define M_  18
#define HW  45056            // 256*176
#define HW4 (HW/4)           // 11264 float4s per plane/channel
#define SPLIT 4              // blocks per (b,s,m) plane (divides HW4/TPB = 44)
#define TPB 256
#define CHUNK4 (HW4/SPLIT)   // 2816 float4s per block
#define ITERS (CHUNK4/TPB)   // 11 iterations per thread
#define NPLANE (B_*S_*M_)    // 360
#define NBLK (NPLANE*SPLIT)  // 1440 blocks (1440 % 8 == 0 -> bijective XCD swizzle)

// Design ledger (measured on MI355X):
//  - Two kernels, not flag-fused: fusion costs a buffer_wbl2 fence storm
//    (R4: 45us idle) or sc1 scalar-load serialization (R5: 70us).
//  - Champion: R6 = this structure without the mask ring (wall 116.4us).
//  - nt on mask: +8.5us (R9 clean A/B). DEAD.
//  - Mask reg-staging all 11 iters: +8us (R7, VGPR 88 -> occupancy loss).
//  - Forcing VGPR<=32: accumulator spills, 305MB scratch, +130us (R8).
//  - G-sharing via registers (R1/R2: 3x fewer waves) and via L1-lockstep
//    (R10: barrier/iter, FETCH unchanged): both null-to-negative. DEAD.
//  - R4/R7/R10 counters agree: latency-bound wall (VALU<=23%, HBM<=12%,
//    Occ 17-26%) — per-wave outstanding-load depth is the binding resource.
//  - THIS round: depth-2 prefetch ring on the MASK stream only (the one
//    HBM-latency stream; FETCH 36-38MB shows ~58% of the 65MB mask misses
//    L3 to HBM). +8 VGPR, everything else identical to R6.
__global__ __launch_bounds__(TPB) void moments_kernel(
    const float4* __restrict__ X, const float4* __restrict__ Y,
    const float4* __restrict__ Mk, float* __restrict__ part) {
  // XCD-aware bijective swizzle: each XCD's L2 holds ~1 batch of X/Y.
  int wg    = (blockIdx.x & 7) * (NBLK / 8) + (blockIdx.x >> 3);
  int plane = wg / SPLIT;           // (b,s,m)
  int chunk = wg - plane * SPLIT;
  int b     = plane / (S_ * M_);

  const float4* mp = Mk + (size_t)plane * HW4;
  const float4* xp = X  + (size_t)b * (C_ * HW4);
  const float4* yp = Y  + (size_t)b * (C_ * HW4);

  int base = chunk * CHUNK4 + (int)threadIdx.x;

  float aW = 0.f;
  float a1[C_], a2[C_], a11[C_], a22[C_], a12[C_];
#pragma unroll
  for (int c = 0; c < C_; ++c) { a1[c]=a2[c]=a11[c]=a22[c]=a12[c]=0.f; }

  // Mask prefetch ring, depth 2: the load for iter i+2 issues before iter
  // i's compute, so the ~900cyc HBM latency is covered by 2 iterations of
  // own-wave VALU plus co-resident waves. Named registers + full unroll ->
  // static assignment (no scratch; rule: never runtime-index reg arrays).
  float4 wA = mp[base];
  float4 wB = mp[base + TPB];

#pragma unroll
  for (int it = 0; it < ITERS; ++it) {
    int i = base + it * TPB;
    float4 w = wA;
    wA = wB;
    if (it + 2 < ITERS) wB = mp[base + (it + 2) * TPB];

    aW += (w.x + w.y) + (w.z + w.w);
    float wf[4] = {w.x, w.y, w.z, w.w};
#pragma unroll
    for (int c = 0; c < C_; ++c) {
      float4 xv = xp[c * HW4 + i];   // L2-resident streams: compiler-scheduled
      float4 yv = yp[c * HW4 + i];
      float xf[4] = {xv.x, xv.y, xv.z, xv.w};
      float yf[4] = {yv.x, yv.y, yv.z, yv.w};
#pragma unroll
      for (int j = 0; j < 4; ++j) {
        float xc = xf[j], yc = yf[j], wc = wf[j];
        float wx = wc * xc;
        float wy = wc * yc;
        a1 [c] += wx;
        a2 [c] += wy;
        a11[c]  = fmaf(wx, xc, a11[c]);
        a22[c]  = fmaf(wy, yc, a22[c]);
        a12[c]  = fmaf(wx, yc, a12[c]);
      }
    }
  }

  // Pack 16 values: [0]=msum, then per channel {wx, wy, wxx, wyy, wxy} (raw)
  float v[16];
  v[0] = aW;
#pragma unroll
  for (int c = 0; c < C_; ++c) {
    v[1 + c*5 + 0] = a1[c];
    v[1 + c*5 + 1] = a2[c];
    v[1 + c*5 + 2] = a11[c];
    v[1 + c*5 + 3] = a22[c];
    v[1 + c*5 + 4] = a12[c];
  }

  // wave-64 butterfly reduce (amortized over the 11-iter main loop)
#pragma unroll
  for (int off = 32; off > 0; off >>= 1) {
#pragma unroll
    for (int j = 0; j < 16; ++j) v[j] += __shfl_xor(v[j], off);
  }

  __shared__ float red[TPB/64][16];
  int lane = threadIdx.x & 63;
  int wv   = threadIdx.x >> 6;
  if (lane == 0) {
#pragma unroll
    for (int j = 0; j < 16; ++j) red[wv][j] = v[j];
  }
  __syncthreads();
  if (threadIdx.x < 16) {
    float s = (red[0][threadIdx.x] + red[1][threadIdx.x]) +
              (red[2][threadIdx.x] + red[3][threadIdx.x]);
    part[(size_t)wg * 16 + threadIdx.x] = s;
  }
}

// Kernel B: tiny epilogue, one block. Plain loads (kernel-boundary coherence).
// Exact affine rescale of raw moments in double:
//   xs = 0.5x + 0.5  =>  E[w*xs]    = 0.5*S1 + 0.5*W
//                        E[w*xs^2]  = 0.25*S11 + 0.5*S1 + 0.25*W
//                        E[w*xs*ys] = 0.25*(S12 + S1 + S2 + W)
__global__ __launch_bounds__(384) void finalize_kernel(
    const float* __restrict__ part, float* __restrict__ out) {
  __shared__ float csS[NPLANE], ssS[NPLANE];
  __shared__ double csb[B_*S_], ssb[B_*S_];
  int t = threadIdx.x;

  if (t < NPLANE) {
    double s[16];
#pragma unroll
    for (int j = 0; j < 16; ++j) s[j] = 0.0;
    for (int ch = 0; ch < SPLIT; ++ch) {
      const float* p = part + (size_t)(t * SPLIT + ch) * 16;
#pragma unroll
      for (int j = 0; j < 16; ++j) s[j] += (double)p[j];
    }
    const double C1d = 1e-4, C2d = 9e-4;
    double W = s[0];
    double inv = 1.0 / (W + 1e-6);
    double csAcc = 0.0, ssAcc = 0.0;
#pragma unroll
    for (int c = 0; c < C_; ++c) {
      double S1  = s[1 + c*5 + 0];
      double S2  = s[1 + c*5 + 1];
      double S11 = s[1 + c*5 + 2];
      double S22 = s[1 + c*5 + 3];
      double S12 = s[1 + c*5 + 4];
      double mu1  = (0.5*S1 + 0.5*W) * inv;
      double mu2  = (0.5*S2 + 0.5*W) * inv;
      double mu11 = (0.25*S11 + 0.5*S1 + 0.25*W) * inv;
      double mu22 = (0.25*S22 + 0.5*S2 + 0.25*W) * inv;
      double mu12 = (0.25*(S12 + S1 + S2 + W)) * inv;
      double m1s = mu1*mu1, m2s = mu2*mu2, m12 = mu1*mu2;
      double sig1  = mu11 - m1s;
      double sig2  = mu22 - m2s;
      double sig12 = mu12 - m12;
      double cs   = (2.0*sig12 + C2d) / (sig1 + sig2 + C2d);
      double ssim = (2.0*m12 + C1d) / (m1s + m2s + C1d) * cs;
      if (cs   < 0.0) cs   = 0.0;
      if (ssim < 0.0) ssim = 0.0;
      csAcc += cs; ssAcc += ssim;
    }
    csS[t] = (float)csAcc;
    ssS[t] = (float)ssAcc;
  }
  __syncthreads();

  if (t < B_*S_) {  // t = b*S_ + s
    double cb = 0.0, sb = 0.0;
    for (int m = 0; m < M_; ++m) { cb += (double)csS[t*M_ + m]; sb += (double)ssS[t*M_ + m]; }
    csb[t] = cb / (double)(M_*C_);
    ssb[t] = sb / (double)(M_*C_);
  }
  __syncthreads();

  if (t == 0) {
    double acc = 0.0;
    for (int b = 0; b < B_; ++b) {
      double p = ssb[b*S_ + (S_-1)];
      for (int s = 0; s < S_-1; ++s) p *= csb[b*S_ + s];
      acc += p;
    }
    out[0] = (float)(acc / (double)B_);
  }
}

extern "C" void kernel_launch(void* const* d_in, const int* in_sizes, int n_in,
                              void* d_out, int out_size, void* d_ws, size_t ws_size,
                              hipStream_t stream) {
  (void)in_sizes; (void)n_in; (void)out_size; (void)ws_size;
  const float4* X  = (const float4*)d_in[0];
  const float4* Y  = (const float4*)d_in[1];
  const float4* Mk = (const float4*)d_in[2];
  float* part = (float*)d_ws;        // 1440*16*4 = 92160 B
  float* out  = (float*)d_out;

  hipLaunchKernelGGL(moments_kernel, dim3(NBLK), dim3(TPB), 0, stream,
                     X, Y, Mk, part);
  hipLaunchKernelGGL(finalize_kernel, dim3(1), dim3(384), 0, stream, part, out);
}